// Round 6
// baseline (508.609 us; speedup 1.0000x reference)
//
#include <hip/hip_runtime.h>
#include <math.h>

// Problem constants (from reference)
#define N_NODES 50000
#define N_EDGES 800000
#define ET (N_EDGES + N_NODES)   // edges + self loops = 850000
#define IN_DIM 128
#define HID 128
#define OUT_DIM 64
#define SCAN_NB ((N_NODES + 255) / 256)   // 196 scan blocks
#define BW 64                              // scatter bucket width (dst nodes)
#define NBUCK ((N_NODES + BW - 1) / BW)    // 782 buckets

__device__ __forceinline__ float lrelu(float x){ return x >= 0.f ? x : 0.2f * x; }
__device__ __forceinline__ float eluf(float x){ return x > 0.f ? x : expm1f(x); }
// RNE float->bf16 (finite inputs)
__device__ __forceinline__ unsigned f2bf(float f){
    unsigned u = __float_as_uint(f);
    return (u + 0x7fffu + ((u >> 16) & 1u)) >> 16;
}
__device__ __forceinline__ float bflo(unsigned u){ return __uint_as_float(u << 16); }
__device__ __forceinline__ float bfhi(unsigned u){ return __uint_as_float(u & 0xffff0000u); }

// ---------------------------------------------------------------------------
// CSR build: histogram -> 3-phase scan -> two-level bucketed scatter.
// ---------------------------------------------------------------------------
__global__ __launch_bounds__(256) void k_hist(const int* __restrict__ dst, int* __restrict__ deg)
{
    const int e = blockIdx.x * 256 + threadIdx.x;
    if (e >= ET) return;
    const int d = (e < N_EDGES) ? dst[e] : (e - N_EDGES);
    atomicAdd(&deg[d], 1);
}

__global__ __launch_bounds__(256) void k_scanA(const int* __restrict__ deg, int* __restrict__ bsum)
{
    __shared__ int red[4];
    const int idx = blockIdx.x * 256 + threadIdx.x;
    int v = (idx < N_NODES) ? deg[idx] : 0;
    #pragma unroll
    for (int off = 32; off > 0; off >>= 1) v += __shfl_down(v, off);
    if ((threadIdx.x & 63) == 0) red[threadIdx.x >> 6] = v;
    __syncthreads();
    if (threadIdx.x == 0) bsum[blockIdx.x] = red[0] + red[1] + red[2] + red[3];
}

__global__ __launch_bounds__(256) void k_scanB(const int* __restrict__ bsum, int* __restrict__ boff)
{
    __shared__ int part[256];
    const int t = threadIdx.x;
    int v = (t < SCAN_NB) ? bsum[t] : 0;
    part[t] = v;
    __syncthreads();
    #pragma unroll
    for (int d = 1; d < 256; d <<= 1) {
        int add = (t >= d) ? part[t - d] : 0;
        __syncthreads();
        part[t] += add;
        __syncthreads();
    }
    if (t < SCAN_NB) boff[t] = part[t] - v;   // exclusive
}

// Phase C: rowptr/bucket cursors. bcur[b] seeded with rowptr[b*BW].
__global__ __launch_bounds__(256) void k_scanC(const int* __restrict__ deg,
                                               const int* __restrict__ boff,
                                               int* __restrict__ rowptr, int* __restrict__ bcur)
{
    __shared__ int part[256];
    const int t = threadIdx.x;
    const int idx = blockIdx.x * 256 + t;
    int v = (idx < N_NODES) ? deg[idx] : 0;
    part[t] = v;
    __syncthreads();
    #pragma unroll
    for (int d = 1; d < 256; d <<= 1) {
        int add = (t >= d) ? part[t - d] : 0;
        __syncthreads();
        part[t] += add;
        __syncthreads();
    }
    if (idx < N_NODES) {
        const int p = boff[blockIdx.x] + part[t] - v;
        rowptr[idx] = p;
        if ((idx & (BW - 1)) == 0) bcur[idx / BW] = p;   // bucket base cursor
    }
    if (idx == 0) rowptr[N_NODES] = ET;
}

// Pass 1: partition edges into dst-buckets (bucket-major region of part[]).
// 782 moving cursors -> ~50KB active line set -> lines fill before eviction.
__global__ __launch_bounds__(256) void k_part(const int* __restrict__ src,
                                              const int* __restrict__ dst,
                                              int* __restrict__ bcur,
                                              uint2* __restrict__ part)
{
    const int e = blockIdx.x * 256 + threadIdx.x;
    if (e >= ET) return;
    int s, d;
    if (e < N_EDGES) { s = src[e]; d = dst[e]; } else { s = d = e - N_EDGES; }
    const int pos = atomicAdd(&bcur[d / BW], 1);
    part[pos] = make_uint2((unsigned)d, (unsigned)s);
}

// Pass 2: one block per bucket; LDS rank counters; writes confined to the
// bucket's contiguous csr window (~4KB, L2-resident).
__global__ __launch_bounds__(256) void k_scat2(const int* __restrict__ rowptr,
                                               const uint2* __restrict__ part,
                                               int* __restrict__ csr_src)
{
    __shared__ int lcur[BW];
    const int b = blockIdx.x;
    const int n0 = b * BW;
    const int lo = rowptr[n0];
    const int hi = rowptr[min(n0 + BW, N_NODES)];
    if (threadIdx.x < BW) lcur[threadIdx.x] = 0;
    __syncthreads();
    for (int i = lo + threadIdx.x; i < hi; i += 256) {
        const uint2 p = part[i];
        const int d = (int)p.x;
        const int rank = atomicAdd(&lcur[d & (BW - 1)], 1);
        csr_src[rowptr[d] + rank] = (int)p.y;
    }
}

// ---------------------------------------------------------------------------
// K1: h1 = x @ W1 [N,128] -> bf16 table + fp32 logits.
// Register-blocked: 32 nodes/iter, thread = 4 nodes x 4 channels.
// ---------------------------------------------------------------------------
__global__ __launch_bounds__(256, 2) void k_gemm1(
    const float* __restrict__ x, const float* __restrict__ W1,
    const float* __restrict__ a_s, const float* __restrict__ a_d,
    unsigned* __restrict__ h1b, float* __restrict__ as1, float* __restrict__ ad1)
{
    __shared__ float sW[128 * 128];   // 64 KB
    __shared__ float sx[32][128];     // 16 KB
    const int tid = threadIdx.x;
    for (int i = tid; i < 4096; i += 256) ((float4*)sW)[i] = ((const float4*)W1)[i];
    const int cg = tid & 31;          // channels 4cg..4cg+3
    const int ng = tid >> 5;          // node group 0..7 (nodes 4ng..4ng+3)
    const float4 as4 = ((const float4*)a_s)[cg];
    const float4 ad4 = ((const float4*)a_d)[cg];
    const int nGroups = (N_NODES + 31) / 32;   // 1563
    for (int g = blockIdx.x; g < nGroups; g += gridDim.x) {
        const int n0 = g * 32;
        __syncthreads();
        #pragma unroll
        for (int j = 0; j < 4; j++) {
            const int i = tid + 256 * j;
            const int node = i >> 5, quad = i & 31;
            const int n = n0 + node;
            float4 v = make_float4(0.f, 0.f, 0.f, 0.f);
            if (n < N_NODES) v = ((const float4*)x)[n * 32 + quad];
            *(float4*)&sx[node][4 * quad] = v;
        }
        __syncthreads();
        float4 acc[4];
        #pragma unroll
        for (int m = 0; m < 4; m++) acc[m] = make_float4(0.f, 0.f, 0.f, 0.f);
        #pragma unroll 8
        for (int k = 0; k < 128; k++) {
            const float4 w = *(const float4*)&sW[k * 128 + 4 * cg];
            #pragma unroll
            for (int m = 0; m < 4; m++) {
                const float xv = sx[4 * ng + m][k];
                acc[m].x = fmaf(xv, w.x, acc[m].x);
                acc[m].y = fmaf(xv, w.y, acc[m].y);
                acc[m].z = fmaf(xv, w.z, acc[m].z);
                acc[m].w = fmaf(xv, w.w, acc[m].w);
            }
        }
        #pragma unroll
        for (int m = 0; m < 4; m++) {
            const int n = n0 + 4 * ng + m;
            float ps = acc[m].x * as4.x + acc[m].y * as4.y + acc[m].z * as4.z + acc[m].w * as4.w;
            float pd = acc[m].x * ad4.x + acc[m].y * ad4.y + acc[m].z * ad4.z + acc[m].w * ad4.w;
            #pragma unroll
            for (int off = 1; off < 8; off <<= 1) {
                ps += __shfl_xor(ps, off);
                pd += __shfl_xor(pd, off);
            }
            if (n < N_NODES) {
                uint2 pk;
                pk.x = f2bf(acc[m].x) | (f2bf(acc[m].y) << 16);
                pk.y = f2bf(acc[m].z) | (f2bf(acc[m].w) << 16);
                ((uint2*)h1b)[n * 32 + cg] = pk;
                if ((cg & 7) == 0) {
                    as1[n * 4 + (cg >> 3)] = ps;
                    ad1[n * 4 + (cg >> 3)] = pd;
                }
            }
        }
    }
}

// ---------------------------------------------------------------------------
// Aggregation layer 1: 16 threads/node, 8 channels each (4 nodes per wave).
// w computed once per thread, amortized over 8 channels; uint4 gathers.
// ---------------------------------------------------------------------------
__global__ __launch_bounds__(256) void k_aggr1(
    const int* __restrict__ rowptr, const int* __restrict__ csr_src,
    const float* __restrict__ as1, const float* __restrict__ ad1,
    const uint4* __restrict__ h1u4, float* __restrict__ acc1)
{
    const int d  = blockIdx.x * 16 + (threadIdx.x >> 4);   // grid 3125 exact
    const int c8 = threadIdx.x & 15;    // channels 8c8..8c8+7
    const int hd = c8 >> 2;
    const int r0 = rowptr[d], r1 = rowptr[d + 1];
    const float adv = ad1[d * 4 + hd];
    float den = 0.f;
    float acc[8];
    #pragma unroll
    for (int m = 0; m < 8; m++) acc[m] = 0.f;
    int i = r0;
    for (; i + 2 <= r1; i += 2) {
        const int s0 = csr_src[i], s1 = csr_src[i + 1];
        const float e0 = as1[s0 * 4 + hd], e1 = as1[s1 * 4 + hd];
        const uint4 u0 = h1u4[s0 * 16 + c8];
        const uint4 u1 = h1u4[s1 * 16 + c8];
        const float w0 = expf(lrelu(e0 + adv));
        const float w1 = expf(lrelu(e1 + adv));
        den += w0 + w1;
        acc[0] = fmaf(bflo(u0.x), w0, acc[0]); acc[1] = fmaf(bfhi(u0.x), w0, acc[1]);
        acc[2] = fmaf(bflo(u0.y), w0, acc[2]); acc[3] = fmaf(bfhi(u0.y), w0, acc[3]);
        acc[4] = fmaf(bflo(u0.z), w0, acc[4]); acc[5] = fmaf(bfhi(u0.z), w0, acc[5]);
        acc[6] = fmaf(bflo(u0.w), w0, acc[6]); acc[7] = fmaf(bfhi(u0.w), w0, acc[7]);
        acc[0] = fmaf(bflo(u1.x), w1, acc[0]); acc[1] = fmaf(bfhi(u1.x), w1, acc[1]);
        acc[2] = fmaf(bflo(u1.y), w1, acc[2]); acc[3] = fmaf(bfhi(u1.y), w1, acc[3]);
        acc[4] = fmaf(bflo(u1.z), w1, acc[4]); acc[5] = fmaf(bfhi(u1.z), w1, acc[5]);
        acc[6] = fmaf(bflo(u1.w), w1, acc[6]); acc[7] = fmaf(bfhi(u1.w), w1, acc[7]);
    }
    if (i < r1) {
        const int s = csr_src[i];
        const float w = expf(lrelu(as1[s * 4 + hd] + adv));
        const uint4 u = h1u4[s * 16 + c8];
        den += w;
        acc[0] = fmaf(bflo(u.x), w, acc[0]); acc[1] = fmaf(bfhi(u.x), w, acc[1]);
        acc[2] = fmaf(bflo(u.y), w, acc[2]); acc[3] = fmaf(bfhi(u.y), w, acc[3]);
        acc[4] = fmaf(bflo(u.z), w, acc[4]); acc[5] = fmaf(bfhi(u.z), w, acc[5]);
        acc[6] = fmaf(bflo(u.w), w, acc[6]); acc[7] = fmaf(bfhi(u.w), w, acc[7]);
    }
    const float inv = 1.f / (den + 1e-16f);
    float4 o0 = make_float4(acc[0] * inv, acc[1] * inv, acc[2] * inv, acc[3] * inv);
    float4 o1 = make_float4(acc[4] * inv, acc[5] * inv, acc[6] * inv, acc[7] * inv);
    ((float4*)acc1)[d * 32 + 2 * c8 + 0] = o0;
    ((float4*)acc1)[d * 32 + 2 * c8 + 1] = o1;
}

// ---------------------------------------------------------------------------
// K4: hE = elu(acc1+b1); h2 = hE @ W2 [N,64] -> bf16 table + fp32 logits.
// Register-blocked: 64 nodes/iter, thread = 4 nodes x 4 channels.
// ---------------------------------------------------------------------------
__global__ __launch_bounds__(256, 2) void k_layer2(
    const float* __restrict__ acc1, const float* __restrict__ b1,
    const float* __restrict__ W2, const float* __restrict__ a_s2, const float* __restrict__ a_d2,
    unsigned* __restrict__ h2b, float* __restrict__ as2, float* __restrict__ ad2)
{
    __shared__ float sW[128 * 64];    // 32 KB
    __shared__ float sh[64][132];     // 33.8 KB
    const int tid = threadIdx.x;
    for (int i = tid; i < 2048; i += 256) ((float4*)sW)[i] = ((const float4*)W2)[i];
    const int cg = tid & 15;          // channels 4cg..4cg+3
    const int ng = tid >> 4;          // node group 0..15
    const float4 as4 = ((const float4*)a_s2)[cg];
    const float4 ad4 = ((const float4*)a_d2)[cg];
    const int nGroups = (N_NODES + 63) / 64;   // 782
    for (int g = blockIdx.x; g < nGroups; g += gridDim.x) {
        const int n0 = g * 64;
        __syncthreads();
        #pragma unroll
        for (int j = 0; j < 8; j++) {
            const int i = tid + 256 * j;
            const int node = i >> 5, quad = i & 31;
            const int n = n0 + node;
            float4 v = make_float4(0.f, 0.f, 0.f, 0.f);
            if (n < N_NODES) {
                v = ((const float4*)acc1)[n * 32 + quad];
                const float4 bb = ((const float4*)b1)[quad];
                v.x = eluf(v.x + bb.x);
                v.y = eluf(v.y + bb.y);
                v.z = eluf(v.z + bb.z);
                v.w = eluf(v.w + bb.w);
            }
            *(float4*)&sh[node][4 * quad] = v;
        }
        __syncthreads();
        float4 acc[4];
        #pragma unroll
        for (int m = 0; m < 4; m++) acc[m] = make_float4(0.f, 0.f, 0.f, 0.f);
        #pragma unroll 8
        for (int k = 0; k < 128; k++) {
            const float4 w = *(const float4*)&sW[k * 64 + 4 * cg];
            #pragma unroll
            for (int m = 0; m < 4; m++) {
                const float xv = sh[4 * ng + m][k];
                acc[m].x = fmaf(xv, w.x, acc[m].x);
                acc[m].y = fmaf(xv, w.y, acc[m].y);
                acc[m].z = fmaf(xv, w.z, acc[m].z);
                acc[m].w = fmaf(xv, w.w, acc[m].w);
            }
        }
        #pragma unroll
        for (int m = 0; m < 4; m++) {
            const int n = n0 + 4 * ng + m;
            float ps = acc[m].x * as4.x + acc[m].y * as4.y + acc[m].z * as4.z + acc[m].w * as4.w;
            float pd = acc[m].x * ad4.x + acc[m].y * ad4.y + acc[m].z * ad4.z + acc[m].w * ad4.w;
            #pragma unroll
            for (int off = 1; off < 16; off <<= 1) {
                ps += __shfl_xor(ps, off);
                pd += __shfl_xor(pd, off);
            }
            if (n < N_NODES) {
                uint2 pk;
                pk.x = f2bf(acc[m].x) | (f2bf(acc[m].y) << 16);
                pk.y = f2bf(acc[m].z) | (f2bf(acc[m].w) << 16);
                ((uint2*)h2b)[n * 16 + cg] = pk;
                if (cg == 0) { as2[n] = ps; ad2[n] = pd; }
            }
        }
    }
}

// ---------------------------------------------------------------------------
// Aggregation layer 2: 8 threads/node, 8 channels each (8 nodes per wave).
// ---------------------------------------------------------------------------
__global__ __launch_bounds__(256) void k_aggr2(
    const int* __restrict__ rowptr, const int* __restrict__ csr_src,
    const float* __restrict__ as2, const float* __restrict__ ad2,
    const uint4* __restrict__ h2u4, float* __restrict__ acc2)
{
    const int d  = blockIdx.x * 32 + (threadIdx.x >> 3);
    const int c8 = threadIdx.x & 7;     // channels 8c8..8c8+7
    if (d >= N_NODES) return;
    const int r0 = rowptr[d], r1 = rowptr[d + 1];
    const float adv = ad2[d];
    float den = 0.f;
    float acc[8];
    #pragma unroll
    for (int m = 0; m < 8; m++) acc[m] = 0.f;
    int i = r0;
    for (; i + 2 <= r1; i += 2) {
        const int s0 = csr_src[i], s1 = csr_src[i + 1];
        const float e0 = as2[s0], e1 = as2[s1];
        const uint4 u0 = h2u4[s0 * 8 + c8];
        const uint4 u1 = h2u4[s1 * 8 + c8];
        const float w0 = expf(lrelu(e0 + adv));
        const float w1 = expf(lrelu(e1 + adv));
        den += w0 + w1;
        acc[0] = fmaf(bflo(u0.x), w0, acc[0]); acc[1] = fmaf(bfhi(u0.x), w0, acc[1]);
        acc[2] = fmaf(bflo(u0.y), w0, acc[2]); acc[3] = fmaf(bfhi(u0.y), w0, acc[3]);
        acc[4] = fmaf(bflo(u0.z), w0, acc[4]); acc[5] = fmaf(bfhi(u0.z), w0, acc[5]);
        acc[6] = fmaf(bflo(u0.w), w0, acc[6]); acc[7] = fmaf(bfhi(u0.w), w0, acc[7]);
        acc[0] = fmaf(bflo(u1.x), w1, acc[0]); acc[1] = fmaf(bfhi(u1.x), w1, acc[1]);
        acc[2] = fmaf(bflo(u1.y), w1, acc[2]); acc[3] = fmaf(bfhi(u1.y), w1, acc[3]);
        acc[4] = fmaf(bflo(u1.z), w1, acc[4]); acc[5] = fmaf(bfhi(u1.z), w1, acc[5]);
        acc[6] = fmaf(bflo(u1.w), w1, acc[6]); acc[7] = fmaf(bfhi(u1.w), w1, acc[7]);
    }
    if (i < r1) {
        const int s = csr_src[i];
        const float w = expf(lrelu(as2[s] + adv));
        const uint4 u = h2u4[s * 8 + c8];
        den += w;
        acc[0] = fmaf(bflo(u.x), w, acc[0]); acc[1] = fmaf(bfhi(u.x), w, acc[1]);
        acc[2] = fmaf(bflo(u.y), w, acc[2]); acc[3] = fmaf(bfhi(u.y), w, acc[3]);
        acc[4] = fmaf(bflo(u.z), w, acc[4]); acc[5] = fmaf(bfhi(u.z), w, acc[5]);
        acc[6] = fmaf(bflo(u.w), w, acc[6]); acc[7] = fmaf(bfhi(u.w), w, acc[7]);
    }
    const float inv = 1.f / (den + 1e-16f);
    float4 o0 = make_float4(acc[0] * inv, acc[1] * inv, acc[2] * inv, acc[3] * inv);
    float4 o1 = make_float4(acc[4] * inv, acc[5] * inv, acc[6] * inv, acc[7] * inv);
    ((float4*)acc2)[d * 16 + 2 * c8 + 0] = o0;
    ((float4*)acc2)[d * 16 + 2 * c8 + 1] = o1;
}

// ---------------------------------------------------------------------------
// K7: o = elu(acc2+b2); p = relu(o@pw1+pb1); out = p@pw2+pb2.
// Register-blocked: 64 nodes/iter, thread = 4 nodes x 4 channels per GEMM.
// ---------------------------------------------------------------------------
__global__ __launch_bounds__(256, 2) void k_out(
    const float* __restrict__ acc2, const float* __restrict__ b2,
    const float* __restrict__ pw1, const float* __restrict__ pb1,
    const float* __restrict__ pw2, const float* __restrict__ pb2,
    float* __restrict__ out)
{
    __shared__ float s1[64 * 64];     // 16 KB
    __shared__ float s2[64 * 64];     // 16 KB
    __shared__ float so[64][68];      // 17.4 KB
    __shared__ float sp[64][68];      // 17.4 KB
    const int tid = threadIdx.x;
    for (int i = tid; i < 1024; i += 256) {
        ((float4*)s1)[i] = ((const float4*)pw1)[i];
        ((float4*)s2)[i] = ((const float4*)pw2)[i];
    }
    const int cg = tid & 15;          // channels 4cg..4cg+3
    const int ng = tid >> 4;          // node group 0..15
    const float4 pb1_4 = ((const float4*)pb1)[cg];
    const float4 pb2_4 = ((const float4*)pb2)[cg];
    const int nGroups = (N_NODES + 63) / 64;   // 782
    for (int g = blockIdx.x; g < nGroups; g += gridDim.x) {
        const int n0 = g * 64;
        __syncthreads();
        #pragma unroll
        for (int j = 0; j < 4; j++) {
            const int i = tid + 256 * j;
            const int node = i >> 4, quad = i & 15;
            const int n = n0 + node;
            float4 v = make_float4(0.f, 0.f, 0.f, 0.f);
            if (n < N_NODES) {
                v = ((const float4*)acc2)[n * 16 + quad];
                const float4 bb = ((const float4*)b2)[quad];
                v.x = eluf(v.x + bb.x);
                v.y = eluf(v.y + bb.y);
                v.z = eluf(v.z + bb.z);
                v.w = eluf(v.w + bb.w);
            }
            *(float4*)&so[node][4 * quad] = v;
        }
        __syncthreads();
        float4 p[4];
        #pragma unroll
        for (int m = 0; m < 4; m++) p[m] = pb1_4;
        #pragma unroll 8
        for (int k = 0; k < 64; k++) {
            const float4 w = *(const float4*)&s1[k * 64 + 4 * cg];
            #pragma unroll
            for (int m = 0; m < 4; m++) {
                const float xv = so[4 * ng + m][k];
                p[m].x = fmaf(xv, w.x, p[m].x);
                p[m].y = fmaf(xv, w.y, p[m].y);
                p[m].z = fmaf(xv, w.z, p[m].z);
                p[m].w = fmaf(xv, w.w, p[m].w);
            }
        }
        #pragma unroll
        for (int m = 0; m < 4; m++) {
            p[m].x = fmaxf(p[m].x, 0.f); p[m].y = fmaxf(p[m].y, 0.f);
            p[m].z = fmaxf(p[m].z, 0.f); p[m].w = fmaxf(p[m].w, 0.f);
            *(float4*)&sp[4 * ng + m][4 * cg] = p[m];
        }
        __syncthreads();
        float4 o[4];
        #pragma unroll
        for (int m = 0; m < 4; m++) o[m] = pb2_4;
        #pragma unroll 8
        for (int k = 0; k < 64; k++) {
            const float4 w = *(const float4*)&s2[k * 64 + 4 * cg];
            #pragma unroll
            for (int m = 0; m < 4; m++) {
                const float xv = sp[4 * ng + m][k];
                o[m].x = fmaf(xv, w.x, o[m].x);
                o[m].y = fmaf(xv, w.y, o[m].y);
                o[m].z = fmaf(xv, w.z, o[m].z);
                o[m].w = fmaf(xv, w.w, o[m].w);
            }
        }
        #pragma unroll
        for (int m = 0; m < 4; m++) {
            const int n = n0 + 4 * ng + m;
            if (n < N_NODES) ((float4*)out)[n * 16 + cg] = o[m];
        }
    }
}

// ---------------------------------------------------------------------------
extern "C" void kernel_launch(void* const* d_in, const int* in_sizes, int n_in,
                              void* d_out, int out_size, void* d_ws, size_t ws_size,
                              hipStream_t stream)
{
    const float* x      = (const float*)d_in[0];
    const int*   ei     = (const int*)d_in[1];   // [2, E] int32
    const int*   src    = ei;
    const int*   dst    = ei + N_EDGES;
    const float* W1     = (const float*)d_in[2];
    const float* a_src1 = (const float*)d_in[3];
    const float* a_dst1 = (const float*)d_in[4];
    const float* b1     = (const float*)d_in[5];
    const float* W2     = (const float*)d_in[6];
    const float* a_src2 = (const float*)d_in[7];
    const float* a_dst2 = (const float*)d_in[8];
    const float* b2     = (const float*)d_in[9];
    const float* pw1    = (const float*)d_in[10];
    const float* pb1    = (const float*)d_in[11];
    const float* pw2    = (const float*)d_in[12];
    const float* pb2    = (const float*)d_in[13];

    // Workspace layout (ints). part first for uint2 (8B) alignment.
    uint2* part  = (uint2*)d_ws;          // ET uint2 = 1,700,000 ints
    int* ibase   = (int*)(part + ET);
    int* deg     = ibase;                 // 50,000
    int* rowptr  = deg + 50000;           // 50,001
    int* bsum    = rowptr + 50001;        // 256
    int* boff    = bsum + 256;            // 256
    int* bcur    = boff + 256;            // 782 (pad to 783 for even total)
    int* csr_src = bcur + 783;            // 850,000
    // offset here: 1,700,000+50,000+50,001+256+256+783+850,000 = 2,651,296 (div 4 -> 16B ok)
    unsigned* h1b = (unsigned*)(csr_src + 850000);  // N*64 uints (bf16 x2)
    unsigned* h2b = h1b + 3200000;                  // N*32 uints
    float* fws   = (float*)(h2b + 1600000);
    float* as1   = fws;                   // N*4
    float* ad1   = as1 + 200000;          // N*4
    float* acc1  = ad1 + 200000;          // N*128
    float* as2   = acc1 + 6400000;        // N
    float* ad2   = as2 + 50000;           // N
    float* acc2  = ad2 + 50000;           // N*64
    // total ~ 70 MB

    // CSR build (reused by both layers)
    hipMemsetAsync(deg, 0, 50000 * sizeof(int), stream);
    k_hist<<<(ET + 255) / 256, 256, 0, stream>>>(dst, deg);
    k_scanA<<<SCAN_NB, 256, 0, stream>>>(deg, bsum);
    k_scanB<<<1, 256, 0, stream>>>(bsum, boff);
    k_scanC<<<SCAN_NB, 256, 0, stream>>>(deg, boff, rowptr, bcur);
    k_part<<<(ET + 255) / 256, 256, 0, stream>>>(src, dst, bcur, part);
    k_scat2<<<NBUCK, 256, 0, stream>>>(rowptr, part, csr_src);

    // Layer 1
    k_gemm1<<<1563, 256, 0, stream>>>(x, W1, a_src1, a_dst1, h1b, as1, ad1);
    k_aggr1<<<N_NODES / 16, 256, 0, stream>>>(rowptr, csr_src, as1, ad1,
                                              (const uint4*)h1b, acc1);

    // Layer 2
    k_layer2<<<782, 256, 0, stream>>>(acc1, b1, W2, a_src2, a_dst2, h2b, as2, ad2);
    k_aggr2<<<(N_NODES + 31) / 32, 256, 0, stream>>>(rowptr, csr_src, as2, ad2,
                                                     (const uint4*)h2b, acc2);

    // Output MLP
    k_out<<<782, 256, 0, stream>>>(acc2, b2, pw1, pb1, pw2, pb2, (float*)d_out);
}

// Round 7
// 274.477 us; speedup vs baseline: 1.8530x; 1.8530x over previous
//
#include <hip/hip_runtime.h>
#include <math.h>

// Problem constants (from reference)
#define N_NODES 50000
#define N_EDGES 800000
#define ET (N_EDGES + N_NODES)   // edges + self loops = 850000
#define IN_DIM 128
#define HID 128
#define OUT_DIM 64
#define BW 64                              // bucket width (dst nodes)
#define NBUCK ((N_NODES + BW - 1) / BW)    // 782 buckets
#define NBLK 256                           // partition blocks
#define EPB 3328                           // edges per partition block (13*256); 256*3328 >= ET

__device__ __forceinline__ float lrelu(float x){ return x >= 0.f ? x : 0.2f * x; }
__device__ __forceinline__ float eluf(float x){ return x > 0.f ? x : expm1f(x); }
// RNE float->bf16 (finite inputs)
__device__ __forceinline__ unsigned f2bf(float f){
    unsigned u = __float_as_uint(f);
    return (u + 0x7fffu + ((u >> 16) & 1u)) >> 16;
}
__device__ __forceinline__ float bflo(unsigned u){ return __uint_as_float(u << 16); }
__device__ __forceinline__ float bfhi(unsigned u){ return __uint_as_float(u & 0xffff0000u); }

// ---------------------------------------------------------------------------
// CSR build, atomic-free radix style:
//   k_count -> C[bucket][block]   (LDS histogram per block)
//   k_bsumA/k_bscanB/k_cscanC     (scan: bucket bases boff2 + per-block bases Cs)
//   k_part2 -> part[] (d,s) bucket-major, deterministic offsets
//   k_scat2 -> rowptr + csr_src   (per-bucket node counts, wave scan, rank)
// ---------------------------------------------------------------------------
__global__ __launch_bounds__(256) void k_count(const int* __restrict__ dst, int* __restrict__ C)
{
    __shared__ int cnt[NBUCK];
    const int tid = threadIdx.x, blk = blockIdx.x;
    for (int i = tid; i < NBUCK; i += 256) cnt[i] = 0;
    __syncthreads();
    #pragma unroll
    for (int j = 0; j < EPB / 256; j++) {
        const int e = blk * EPB + j * 256 + tid;
        if (e < ET) {
            const int d = (e < N_EDGES) ? dst[e] : (e - N_EDGES);
            atomicAdd(&cnt[d >> 6], 1);
        }
    }
    __syncthreads();
    for (int b = tid; b < NBUCK; b += 256) C[b * NBLK + blk] = cnt[b];
}

// Per-bucket totals: block b sums C[b*NBLK .. +255].
__global__ __launch_bounds__(256) void k_bsumA(const int* __restrict__ C, int* __restrict__ bsum2)
{
    __shared__ int red[4];
    int v = C[blockIdx.x * NBLK + threadIdx.x];
    #pragma unroll
    for (int off = 32; off > 0; off >>= 1) v += __shfl_down(v, off);
    if ((threadIdx.x & 63) == 0) red[threadIdx.x >> 6] = v;
    __syncthreads();
    if (threadIdx.x == 0) bsum2[blockIdx.x] = red[0] + red[1] + red[2] + red[3];
}

// Exclusive scan of 782 bucket totals -> bucket bases boff2[0..NBUCK].
__global__ __launch_bounds__(1024) void k_bscanB(const int* __restrict__ bsum2, int* __restrict__ boff2)
{
    __shared__ int part[1024];
    const int t = threadIdx.x;
    int v = (t < NBUCK) ? bsum2[t] : 0;
    part[t] = v;
    __syncthreads();
    #pragma unroll
    for (int d = 1; d < 1024; d <<= 1) {
        int add = (t >= d) ? part[t - d] : 0;
        __syncthreads();
        part[t] += add;
        __syncthreads();
    }
    if (t < NBUCK) boff2[t] = part[t] - v;   // exclusive
    if (t == 0) boff2[NBUCK] = ET;
}

// Within-bucket exclusive scan over blocks: Cs[b][blk] = boff2[b] + prefix.
__global__ __launch_bounds__(256) void k_cscanC(const int* __restrict__ C,
                                                const int* __restrict__ boff2,
                                                int* __restrict__ Cs)
{
    __shared__ int part[256];
    const int t = threadIdx.x, b = blockIdx.x;
    int v = C[b * NBLK + t];
    part[t] = v;
    __syncthreads();
    #pragma unroll
    for (int d = 1; d < 256; d <<= 1) {
        int add = (t >= d) ? part[t - d] : 0;
        __syncthreads();
        part[t] += add;
        __syncthreads();
    }
    Cs[b * NBLK + t] = boff2[b] + part[t] - v;
}

// Partition: deterministic bases from Cs, ranks via LDS counters. No global atomics.
__global__ __launch_bounds__(256) void k_part2(const int* __restrict__ src,
                                               const int* __restrict__ dst,
                                               const int* __restrict__ Cs,
                                               uint2* __restrict__ part)
{
    __shared__ int base[NBUCK];
    __shared__ int cnt[NBUCK];
    const int tid = threadIdx.x, blk = blockIdx.x;
    for (int b = tid; b < NBUCK; b += 256) { base[b] = Cs[b * NBLK + blk]; cnt[b] = 0; }
    __syncthreads();
    #pragma unroll
    for (int j = 0; j < EPB / 256; j++) {
        const int e = blk * EPB + j * 256 + tid;
        if (e < ET) {
            int s, d;
            if (e < N_EDGES) { s = src[e]; d = dst[e]; } else { s = d = e - N_EDGES; }
            const int b = d >> 6;
            const int r = atomicAdd(&cnt[b], 1);
            part[base[b] + r] = make_uint2((unsigned)d, (unsigned)s);
        }
    }
}

// Per bucket: derive rowptr (bucket base + within-bucket node prefix) and
// rank edges into csr_src. Writes confined to the bucket's contiguous window.
__global__ __launch_bounds__(256) void k_scat2(const int* __restrict__ boff2,
                                               const uint2* __restrict__ part,
                                               int* __restrict__ rowptr,
                                               int* __restrict__ csr_src)
{
    __shared__ int cnt64[BW];
    __shared__ int nbase[BW];
    const int b = blockIdx.x, tid = threadIdx.x;
    const int n0 = b * BW;
    const int lo = boff2[b], hi = boff2[b + 1];
    if (tid < BW) cnt64[tid] = 0;
    __syncthreads();
    for (int i = lo + tid; i < hi; i += 256) {
        atomicAdd(&cnt64[part[i].x & (BW - 1)], 1);
    }
    __syncthreads();
    if (tid < BW) {
        int v = cnt64[tid];
        int incl = v;
        #pragma unroll
        for (int off = 1; off < 64; off <<= 1) {
            int t2 = __shfl_up(incl, off);
            if (tid >= off) incl += t2;
        }
        const int excl = incl - v;
        nbase[tid] = excl;
        const int n = n0 + tid;
        if (n < N_NODES) rowptr[n] = lo + excl;
        cnt64[tid] = 0;
    }
    if (b == 0 && tid == 0) rowptr[N_NODES] = ET;
    __syncthreads();
    for (int i = lo + tid; i < hi; i += 256) {
        const uint2 p = part[i];
        const int dn = (int)p.x & (BW - 1);
        const int r = atomicAdd(&cnt64[dn], 1);
        csr_src[lo + nbase[dn] + r] = (int)p.y;
    }
}

// ---------------------------------------------------------------------------
// K1: h1 = x @ W1 [N,128] -> bf16 table + fp32 logits.
// Register-blocked: 32 nodes/iter, thread = 4 nodes x 4 channels.
// ---------------------------------------------------------------------------
__global__ __launch_bounds__(256, 2) void k_gemm1(
    const float* __restrict__ x, const float* __restrict__ W1,
    const float* __restrict__ a_s, const float* __restrict__ a_d,
    unsigned* __restrict__ h1b, float* __restrict__ as1, float* __restrict__ ad1)
{
    __shared__ float sW[128 * 128];   // 64 KB
    __shared__ float sx[32][128];     // 16 KB
    const int tid = threadIdx.x;
    for (int i = tid; i < 4096; i += 256) ((float4*)sW)[i] = ((const float4*)W1)[i];
    const int cg = tid & 31;          // channels 4cg..4cg+3
    const int ng = tid >> 5;          // node group 0..7 (nodes 4ng..4ng+3)
    const float4 as4 = ((const float4*)a_s)[cg];
    const float4 ad4 = ((const float4*)a_d)[cg];
    const int nGroups = (N_NODES + 31) / 32;   // 1563
    for (int g = blockIdx.x; g < nGroups; g += gridDim.x) {
        const int n0 = g * 32;
        __syncthreads();
        #pragma unroll
        for (int j = 0; j < 4; j++) {
            const int i = tid + 256 * j;
            const int node = i >> 5, quad = i & 31;
            const int n = n0 + node;
            float4 v = make_float4(0.f, 0.f, 0.f, 0.f);
            if (n < N_NODES) v = ((const float4*)x)[n * 32 + quad];
            *(float4*)&sx[node][4 * quad] = v;
        }
        __syncthreads();
        float4 acc[4];
        #pragma unroll
        for (int m = 0; m < 4; m++) acc[m] = make_float4(0.f, 0.f, 0.f, 0.f);
        #pragma unroll 8
        for (int k = 0; k < 128; k++) {
            const float4 w = *(const float4*)&sW[k * 128 + 4 * cg];
            #pragma unroll
            for (int m = 0; m < 4; m++) {
                const float xv = sx[4 * ng + m][k];
                acc[m].x = fmaf(xv, w.x, acc[m].x);
                acc[m].y = fmaf(xv, w.y, acc[m].y);
                acc[m].z = fmaf(xv, w.z, acc[m].z);
                acc[m].w = fmaf(xv, w.w, acc[m].w);
            }
        }
        #pragma unroll
        for (int m = 0; m < 4; m++) {
            const int n = n0 + 4 * ng + m;
            float ps = acc[m].x * as4.x + acc[m].y * as4.y + acc[m].z * as4.z + acc[m].w * as4.w;
            float pd = acc[m].x * ad4.x + acc[m].y * ad4.y + acc[m].z * ad4.z + acc[m].w * ad4.w;
            #pragma unroll
            for (int off = 1; off < 8; off <<= 1) {
                ps += __shfl_xor(ps, off);
                pd += __shfl_xor(pd, off);
            }
            if (n < N_NODES) {
                uint2 pk;
                pk.x = f2bf(acc[m].x) | (f2bf(acc[m].y) << 16);
                pk.y = f2bf(acc[m].z) | (f2bf(acc[m].w) << 16);
                ((uint2*)h1b)[n * 32 + cg] = pk;
                if ((cg & 7) == 0) {
                    as1[n * 4 + (cg >> 3)] = ps;
                    ad1[n * 4 + (cg >> 3)] = pd;
                }
            }
        }
    }
}

// ---------------------------------------------------------------------------
// Aggregation layer 1: 16 threads/node, 8 channels each (4 nodes per wave).
// ---------------------------------------------------------------------------
__global__ __launch_bounds__(256) void k_aggr1(
    const int* __restrict__ rowptr, const int* __restrict__ csr_src,
    const float* __restrict__ as1, const float* __restrict__ ad1,
    const uint4* __restrict__ h1u4, float* __restrict__ acc1)
{
    const int d  = blockIdx.x * 16 + (threadIdx.x >> 4);   // grid 3125 exact
    const int c8 = threadIdx.x & 15;    // channels 8c8..8c8+7
    const int hd = c8 >> 2;
    const int r0 = rowptr[d], r1 = rowptr[d + 1];
    const float adv = ad1[d * 4 + hd];
    float den = 0.f;
    float acc[8];
    #pragma unroll
    for (int m = 0; m < 8; m++) acc[m] = 0.f;
    int i = r0;
    for (; i + 2 <= r1; i += 2) {
        const int s0 = csr_src[i], s1 = csr_src[i + 1];
        const float e0 = as1[s0 * 4 + hd], e1 = as1[s1 * 4 + hd];
        const uint4 u0 = h1u4[s0 * 16 + c8];
        const uint4 u1 = h1u4[s1 * 16 + c8];
        const float w0 = expf(lrelu(e0 + adv));
        const float w1 = expf(lrelu(e1 + adv));
        den += w0 + w1;
        acc[0] = fmaf(bflo(u0.x), w0, acc[0]); acc[1] = fmaf(bfhi(u0.x), w0, acc[1]);
        acc[2] = fmaf(bflo(u0.y), w0, acc[2]); acc[3] = fmaf(bfhi(u0.y), w0, acc[3]);
        acc[4] = fmaf(bflo(u0.z), w0, acc[4]); acc[5] = fmaf(bfhi(u0.z), w0, acc[5]);
        acc[6] = fmaf(bflo(u0.w), w0, acc[6]); acc[7] = fmaf(bfhi(u0.w), w0, acc[7]);
        acc[0] = fmaf(bflo(u1.x), w1, acc[0]); acc[1] = fmaf(bfhi(u1.x), w1, acc[1]);
        acc[2] = fmaf(bflo(u1.y), w1, acc[2]); acc[3] = fmaf(bfhi(u1.y), w1, acc[3]);
        acc[4] = fmaf(bflo(u1.z), w1, acc[4]); acc[5] = fmaf(bfhi(u1.z), w1, acc[5]);
        acc[6] = fmaf(bflo(u1.w), w1, acc[6]); acc[7] = fmaf(bfhi(u1.w), w1, acc[7]);
    }
    if (i < r1) {
        const int s = csr_src[i];
        const float w = expf(lrelu(as1[s * 4 + hd] + adv));
        const uint4 u = h1u4[s * 16 + c8];
        den += w;
        acc[0] = fmaf(bflo(u.x), w, acc[0]); acc[1] = fmaf(bfhi(u.x), w, acc[1]);
        acc[2] = fmaf(bflo(u.y), w, acc[2]); acc[3] = fmaf(bfhi(u.y), w, acc[3]);
        acc[4] = fmaf(bflo(u.z), w, acc[4]); acc[5] = fmaf(bfhi(u.z), w, acc[5]);
        acc[6] = fmaf(bflo(u.w), w, acc[6]); acc[7] = fmaf(bfhi(u.w), w, acc[7]);
    }
    const float inv = 1.f / (den + 1e-16f);
    float4 o0 = make_float4(acc[0] * inv, acc[1] * inv, acc[2] * inv, acc[3] * inv);
    float4 o1 = make_float4(acc[4] * inv, acc[5] * inv, acc[6] * inv, acc[7] * inv);
    ((float4*)acc1)[d * 32 + 2 * c8 + 0] = o0;
    ((float4*)acc1)[d * 32 + 2 * c8 + 1] = o1;
}

// ---------------------------------------------------------------------------
// K4: hE = elu(acc1+b1); h2 = hE @ W2 [N,64] -> bf16 table + fp32 logits.
// Register-blocked: 64 nodes/iter, thread = 4 nodes x 4 channels.
// ---------------------------------------------------------------------------
__global__ __launch_bounds__(256, 2) void k_layer2(
    const float* __restrict__ acc1, const float* __restrict__ b1,
    const float* __restrict__ W2, const float* __restrict__ a_s2, const float* __restrict__ a_d2,
    unsigned* __restrict__ h2b, float* __restrict__ as2, float* __restrict__ ad2)
{
    __shared__ float sW[128 * 64];    // 32 KB
    __shared__ float sh[64][132];     // 33.8 KB
    const int tid = threadIdx.x;
    for (int i = tid; i < 2048; i += 256) ((float4*)sW)[i] = ((const float4*)W2)[i];
    const int cg = tid & 15;          // channels 4cg..4cg+3
    const int ng = tid >> 4;          // node group 0..15
    const float4 as4 = ((const float4*)a_s2)[cg];
    const float4 ad4 = ((const float4*)a_d2)[cg];
    const int nGroups = (N_NODES + 63) / 64;   // 782
    for (int g = blockIdx.x; g < nGroups; g += gridDim.x) {
        const int n0 = g * 64;
        __syncthreads();
        #pragma unroll
        for (int j = 0; j < 8; j++) {
            const int i = tid + 256 * j;
            const int node = i >> 5, quad = i & 31;
            const int n = n0 + node;
            float4 v = make_float4(0.f, 0.f, 0.f, 0.f);
            if (n < N_NODES) {
                v = ((const float4*)acc1)[n * 32 + quad];
                const float4 bb = ((const float4*)b1)[quad];
                v.x = eluf(v.x + bb.x);
                v.y = eluf(v.y + bb.y);
                v.z = eluf(v.z + bb.z);
                v.w = eluf(v.w + bb.w);
            }
            *(float4*)&sh[node][4 * quad] = v;
        }
        __syncthreads();
        float4 acc[4];
        #pragma unroll
        for (int m = 0; m < 4; m++) acc[m] = make_float4(0.f, 0.f, 0.f, 0.f);
        #pragma unroll 8
        for (int k = 0; k < 128; k++) {
            const float4 w = *(const float4*)&sW[k * 64 + 4 * cg];
            #pragma unroll
            for (int m = 0; m < 4; m++) {
                const float xv = sh[4 * ng + m][k];
                acc[m].x = fmaf(xv, w.x, acc[m].x);
                acc[m].y = fmaf(xv, w.y, acc[m].y);
                acc[m].z = fmaf(xv, w.z, acc[m].z);
                acc[m].w = fmaf(xv, w.w, acc[m].w);
            }
        }
        #pragma unroll
        for (int m = 0; m < 4; m++) {
            const int n = n0 + 4 * ng + m;
            float ps = acc[m].x * as4.x + acc[m].y * as4.y + acc[m].z * as4.z + acc[m].w * as4.w;
            float pd = acc[m].x * ad4.x + acc[m].y * ad4.y + acc[m].z * ad4.z + acc[m].w * ad4.w;
            #pragma unroll
            for (int off = 1; off < 16; off <<= 1) {
                ps += __shfl_xor(ps, off);
                pd += __shfl_xor(pd, off);
            }
            if (n < N_NODES) {
                uint2 pk;
                pk.x = f2bf(acc[m].x) | (f2bf(acc[m].y) << 16);
                pk.y = f2bf(acc[m].z) | (f2bf(acc[m].w) << 16);
                ((uint2*)h2b)[n * 16 + cg] = pk;
                if (cg == 0) { as2[n] = ps; ad2[n] = pd; }
            }
        }
    }
}

// ---------------------------------------------------------------------------
// Aggregation layer 2: 8 threads/node, 8 channels each (8 nodes per wave).
// ---------------------------------------------------------------------------
__global__ __launch_bounds__(256) void k_aggr2(
    const int* __restrict__ rowptr, const int* __restrict__ csr_src,
    const float* __restrict__ as2, const float* __restrict__ ad2,
    const uint4* __restrict__ h2u4, float* __restrict__ acc2)
{
    const int d  = blockIdx.x * 32 + (threadIdx.x >> 3);
    const int c8 = threadIdx.x & 7;     // channels 8c8..8c8+7
    if (d >= N_NODES) return;
    const int r0 = rowptr[d], r1 = rowptr[d + 1];
    const float adv = ad2[d];
    float den = 0.f;
    float acc[8];
    #pragma unroll
    for (int m = 0; m < 8; m++) acc[m] = 0.f;
    int i = r0;
    for (; i + 2 <= r1; i += 2) {
        const int s0 = csr_src[i], s1 = csr_src[i + 1];
        const float e0 = as2[s0], e1 = as2[s1];
        const uint4 u0 = h2u4[s0 * 8 + c8];
        const uint4 u1 = h2u4[s1 * 8 + c8];
        const float w0 = expf(lrelu(e0 + adv));
        const float w1 = expf(lrelu(e1 + adv));
        den += w0 + w1;
        acc[0] = fmaf(bflo(u0.x), w0, acc[0]); acc[1] = fmaf(bfhi(u0.x), w0, acc[1]);
        acc[2] = fmaf(bflo(u0.y), w0, acc[2]); acc[3] = fmaf(bfhi(u0.y), w0, acc[3]);
        acc[4] = fmaf(bflo(u0.z), w0, acc[4]); acc[5] = fmaf(bfhi(u0.z), w0, acc[5]);
        acc[6] = fmaf(bflo(u0.w), w0, acc[6]); acc[7] = fmaf(bfhi(u0.w), w0, acc[7]);
        acc[0] = fmaf(bflo(u1.x), w1, acc[0]); acc[1] = fmaf(bfhi(u1.x), w1, acc[1]);
        acc[2] = fmaf(bflo(u1.y), w1, acc[2]); acc[3] = fmaf(bfhi(u1.y), w1, acc[3]);
        acc[4] = fmaf(bflo(u1.z), w1, acc[4]); acc[5] = fmaf(bfhi(u1.z), w1, acc[5]);
        acc[6] = fmaf(bflo(u1.w), w1, acc[6]); acc[7] = fmaf(bfhi(u1.w), w1, acc[7]);
    }
    if (i < r1) {
        const int s = csr_src[i];
        const float w = expf(lrelu(as2[s] + adv));
        const uint4 u = h2u4[s * 8 + c8];
        den += w;
        acc[0] = fmaf(bflo(u.x), w, acc[0]); acc[1] = fmaf(bfhi(u.x), w, acc[1]);
        acc[2] = fmaf(bflo(u.y), w, acc[2]); acc[3] = fmaf(bfhi(u.y), w, acc[3]);
        acc[4] = fmaf(bflo(u.z), w, acc[4]); acc[5] = fmaf(bfhi(u.z), w, acc[5]);
        acc[6] = fmaf(bflo(u.w), w, acc[6]); acc[7] = fmaf(bfhi(u.w), w, acc[7]);
    }
    const float inv = 1.f / (den + 1e-16f);
    float4 o0 = make_float4(acc[0] * inv, acc[1] * inv, acc[2] * inv, acc[3] * inv);
    float4 o1 = make_float4(acc[4] * inv, acc[5] * inv, acc[6] * inv, acc[7] * inv);
    ((float4*)acc2)[d * 16 + 2 * c8 + 0] = o0;
    ((float4*)acc2)[d * 16 + 2 * c8 + 1] = o1;
}

// ---------------------------------------------------------------------------
// K7: o = elu(acc2+b2); p = relu(o@pw1+pb1); out = p@pw2+pb2.
// Register-blocked: 64 nodes/iter, thread = 4 nodes x 4 channels per GEMM.
// ---------------------------------------------------------------------------
__global__ __launch_bounds__(256, 2) void k_out(
    const float* __restrict__ acc2, const float* __restrict__ b2,
    const float* __restrict__ pw1, const float* __restrict__ pb1,
    const float* __restrict__ pw2, const float* __restrict__ pb2,
    float* __restrict__ out)
{
    __shared__ float s1[64 * 64];     // 16 KB
    __shared__ float s2[64 * 64];     // 16 KB
    __shared__ float so[64][68];      // 17.4 KB
    __shared__ float sp[64][68];      // 17.4 KB
    const int tid = threadIdx.x;
    for (int i = tid; i < 1024; i += 256) {
        ((float4*)s1)[i] = ((const float4*)pw1)[i];
        ((float4*)s2)[i] = ((const float4*)pw2)[i];
    }
    const int cg = tid & 15;          // channels 4cg..4cg+3
    const int ng = tid >> 4;          // node group 0..15
    const float4 pb1_4 = ((const float4*)pb1)[cg];
    const float4 pb2_4 = ((const float4*)pb2)[cg];
    const int nGroups = (N_NODES + 63) / 64;   // 782
    for (int g = blockIdx.x; g < nGroups; g += gridDim.x) {
        const int n0 = g * 64;
        __syncthreads();
        #pragma unroll
        for (int j = 0; j < 4; j++) {
            const int i = tid + 256 * j;
            const int node = i >> 4, quad = i & 15;
            const int n = n0 + node;
            float4 v = make_float4(0.f, 0.f, 0.f, 0.f);
            if (n < N_NODES) {
                v = ((const float4*)acc2)[n * 16 + quad];
                const float4 bb = ((const float4*)b2)[quad];
                v.x = eluf(v.x + bb.x);
                v.y = eluf(v.y + bb.y);
                v.z = eluf(v.z + bb.z);
                v.w = eluf(v.w + bb.w);
            }
            *(float4*)&so[node][4 * quad] = v;
        }
        __syncthreads();
        float4 p[4];
        #pragma unroll
        for (int m = 0; m < 4; m++) p[m] = pb1_4;
        #pragma unroll 8
        for (int k = 0; k < 64; k++) {
            const float4 w = *(const float4*)&s1[k * 64 + 4 * cg];
            #pragma unroll
            for (int m = 0; m < 4; m++) {
                const float xv = so[4 * ng + m][k];
                p[m].x = fmaf(xv, w.x, p[m].x);
                p[m].y = fmaf(xv, w.y, p[m].y);
                p[m].z = fmaf(xv, w.z, p[m].z);
                p[m].w = fmaf(xv, w.w, p[m].w);
            }
        }
        #pragma unroll
        for (int m = 0; m < 4; m++) {
            p[m].x = fmaxf(p[m].x, 0.f); p[m].y = fmaxf(p[m].y, 0.f);
            p[m].z = fmaxf(p[m].z, 0.f); p[m].w = fmaxf(p[m].w, 0.f);
            *(float4*)&sp[4 * ng + m][4 * cg] = p[m];
        }
        __syncthreads();
        float4 o[4];
        #pragma unroll
        for (int m = 0; m < 4; m++) o[m] = pb2_4;
        #pragma unroll 8
        for (int k = 0; k < 64; k++) {
            const float4 w = *(const float4*)&s2[k * 64 + 4 * cg];
            #pragma unroll
            for (int m = 0; m < 4; m++) {
                const float xv = sp[4 * ng + m][k];
                o[m].x = fmaf(xv, w.x, o[m].x);
                o[m].y = fmaf(xv, w.y, o[m].y);
                o[m].z = fmaf(xv, w.z, o[m].z);
                o[m].w = fmaf(xv, w.w, o[m].w);
            }
        }
        #pragma unroll
        for (int m = 0; m < 4; m++) {
            const int n = n0 + 4 * ng + m;
            if (n < N_NODES) ((float4*)out)[n * 16 + cg] = o[m];
        }
    }
}

// ---------------------------------------------------------------------------
extern "C" void kernel_launch(void* const* d_in, const int* in_sizes, int n_in,
                              void* d_out, int out_size, void* d_ws, size_t ws_size,
                              hipStream_t stream)
{
    const float* x      = (const float*)d_in[0];
    const int*   ei     = (const int*)d_in[1];   // [2, E] int32
    const int*   src    = ei;
    const int*   dst    = ei + N_EDGES;
    const float* W1     = (const float*)d_in[2];
    const float* a_src1 = (const float*)d_in[3];
    const float* a_dst1 = (const float*)d_in[4];
    const float* b1     = (const float*)d_in[5];
    const float* W2     = (const float*)d_in[6];
    const float* a_src2 = (const float*)d_in[7];
    const float* a_dst2 = (const float*)d_in[8];
    const float* b2     = (const float*)d_in[9];
    const float* pw1    = (const float*)d_in[10];
    const float* pb1    = (const float*)d_in[11];
    const float* pw2    = (const float*)d_in[12];
    const float* pb2    = (const float*)d_in[13];

    // Workspace layout. part first (8B align from d_ws base).
    uint2* part  = (uint2*)d_ws;          // ET uint2 = 1,700,000 ints
    int* ibase   = (int*)(part + ET);
    int* rowptr  = ibase;                 // 50,001
    int* C       = rowptr + 50001;        // NBUCK*NBLK = 200,192
    int* Cs      = C + 200192;            // 200,192
    int* bsum2   = Cs + 200192;           // 782
    int* boff2   = bsum2 + 782;           // 783 (+2 pad -> 785)
    int* csr_src = boff2 + 785;           // 850,000
    // int offset so far: 1,700,000+50,001+200,192+200,192+782+785+850,000
    //                  = 3,001,952 ints (x4 = 12,007,808 B, 16B aligned)
    unsigned* h1b = (unsigned*)(csr_src + 850000);  // N*64 uints (bf16 x2)
    unsigned* h2b = h1b + 3200000;                  // N*32 uints
    float* fws   = (float*)(h2b + 1600000);
    float* as1   = fws;                   // N*4
    float* ad1   = as1 + 200000;          // N*4
    float* acc1  = ad1 + 200000;          // N*128
    float* as2   = acc1 + 6400000;        // N
    float* ad2   = as2 + 50000;           // N
    float* acc2  = ad2 + 50000;           // N*64
    // total ~ 72 MB

    // CSR build — atomic-free radix partition (reused by both layers).
    k_count<<<NBLK, 256, 0, stream>>>(dst, C);
    k_bsumA<<<NBUCK, 256, 0, stream>>>(C, bsum2);
    k_bscanB<<<1, 1024, 0, stream>>>(bsum2, boff2);
    k_cscanC<<<NBUCK, 256, 0, stream>>>(C, boff2, Cs);
    k_part2<<<NBLK, 256, 0, stream>>>(src, dst, Cs, part);
    k_scat2<<<NBUCK, 256, 0, stream>>>(boff2, part, rowptr, csr_src);

    // Layer 1
    k_gemm1<<<1563, 256, 0, stream>>>(x, W1, a_src1, a_dst1, h1b, as1, ad1);
    k_aggr1<<<N_NODES / 16, 256, 0, stream>>>(rowptr, csr_src, as1, ad1,
                                              (const uint4*)h1b, acc1);

    // Layer 2
    k_layer2<<<782, 256, 0, stream>>>(acc1, b1, W2, a_src2, a_dst2, h2b, as2, ad2);
    k_aggr2<<<(N_NODES + 31) / 32, 256, 0, stream>>>(rowptr, csr_src, as2, ad2,
                                                     (const uint4*)h2b, acc2);

    // Output MLP
    k_out<<<782, 256, 0, stream>>>(acc2, b2, pw1, pb1, pw2, pb2, (float*)d_out);
}